// Round 12
// baseline (71.495 us; speedup 1.0000x reference)
//
#include <hip/hip_runtime.h>
#include <hip/hip_bf16.h>
#include <stdint.h>

#define BATCH 16
#define NDIM  2048
#define MDIM  2048
#define DDIM  128   // LD == RD == 128

using bf16x8 = __attribute__((ext_vector_type(8))) short;
using bf16x4 = __attribute__((ext_vector_type(4))) short;  // 8 B
using f32x4  = __attribute__((ext_vector_type(4))) float;

// async global->LDS, 16B per lane; LDS dest is wave-uniform base + lane*16
#define GLOAD_LDS16(g, l) __builtin_amdgcn_global_load_lds( \
    (const __attribute__((address_space(1))) void*)(g),      \
    (__attribute__((address_space(3))) void*)(l), 16, 0, 0)

__device__ __forceinline__ unsigned short f2bf(float f) {
    unsigned u = __float_as_uint(f);
    u += 0x7fffu + ((u >> 16) & 1u);   // round-to-nearest-even
    return (unsigned short)(u >> 16);
}

// ---------------------------------------------------------------------------
// Stage ROWS x 128 f32 (row stride 128 floats) into LDS as bf16 with the
// XOR-16B-chunk swizzle: logical chunk (row, ks) -> byte
//   row*256 + (ks ^ (row & 15)) * 16.
// ---------------------------------------------------------------------------
template <int ITERS>
__device__ __forceinline__ void stage_f32_tile(const float* __restrict__ g,
                                               char* lds, int t) {
    #pragma unroll
    for (int it = 0; it < ITERS; ++it) {
        const int idx = it * 256 + t;           // 16B-bf16-chunk index
        const int row = idx >> 4, ks = idx & 15;
        const float4* p = (const float4*)(g + row * 128 + ks * 8);
        float4 v0 = p[0], v1 = p[1];
        bf16x8 r;
        r[0] = f2bf(v0.x); r[1] = f2bf(v0.y); r[2] = f2bf(v0.z); r[3] = f2bf(v0.w);
        r[4] = f2bf(v1.x); r[5] = f2bf(v1.y); r[6] = f2bf(v1.z); r[7] = f2bf(v1.w);
        *(bf16x8*)(lds + row * 256 + ((ks ^ (row & 15)) * 16)) = r;
    }
}

// ---------------------------------------------------------------------------
// Kernel 1 (prep): UNCHANGED from R9-R11. 512 blocks (2/CU). Per block br:
//   a) cw[br*64+m][i] = sum_j crit[br*64+m][j] * W[i][j]   (64-row tile)
//   b) grid-stride convert data f32 -> bf16.
// ---------------------------------------------------------------------------
extern "C" __global__ __launch_bounds__(256)
void bd_prep_kernel(const float* __restrict__ data,
                    const float* __restrict__ crit,
                    const float* __restrict__ W,
                    unsigned short* __restrict__ cw,
                    unsigned short* __restrict__ data_b) {
    __shared__ __align__(16) char smem[49152];
    const int t    = threadIdx.x;
    const int lane = t & 63;
    const int w    = t >> 6;
    const int wr = w >> 1, wc = w & 1;
    const int lrow = lane & 15;
    const int lk   = lane >> 4;
    const int br = blockIdx.x;  // 0..511

    stage_f32_tile<8>(W, smem, t);
    stage_f32_tile<4>(crit + (size_t)br * 64 * DDIM, smem + 32768, t);
    __syncthreads();

    // acc1[x][y]: i = wr*64 + x*16 + lk*4 + j, m = wc*32 + y*16 + lrow
    f32x4 acc1[4][2];
    #pragma unroll
    for (int x = 0; x < 4; ++x) {
        acc1[x][0] = (f32x4){0.f, 0.f, 0.f, 0.f};
        acc1[x][1] = (f32x4){0.f, 0.f, 0.f, 0.f};
    }

    #pragma unroll
    for (int ks = 0; ks < 4; ++ks) {
        const int ksl = ks * 4 + lk;
        bf16x8 a1[4], b1[2];
        #pragma unroll
        for (int x = 0; x < 4; ++x) {           // W rows (i)
            const int r = wr * 64 + x * 16 + lrow;
            a1[x] = *(const bf16x8*)(smem + r * 256 + ((ksl ^ (r & 15)) * 16));
        }
        #pragma unroll
        for (int y = 0; y < 2; ++y) {           // crit rows (m)
            const int r = wc * 32 + y * 16 + lrow;
            b1[y] = *(const bf16x8*)(smem + 32768 + r * 256 + ((ksl ^ (r & 15)) * 16));
        }
        #pragma unroll
        for (int x = 0; x < 4; ++x)
            #pragma unroll
            for (int y = 0; y < 2; ++y)
                acc1[x][y] = __builtin_amdgcn_mfma_f32_16x16x32_bf16(
                    a1[x], b1[y], acc1[x][y], 0, 0, 0);
    }

    // cw[m][i]: m = wc*32+y*16+lrow, i = wr*64+x*16+lk*4+j -> 8-B stores
    unsigned short* Cb = cw + (size_t)br * 64 * 128;
    #pragma unroll
    for (int x = 0; x < 4; ++x)
        #pragma unroll
        for (int y = 0; y < 2; ++y) {
            bf16x4 v;
            v[0] = f2bf(acc1[x][y][0]);
            v[1] = f2bf(acc1[x][y][1]);
            v[2] = f2bf(acc1[x][y][2]);
            v[3] = f2bf(acc1[x][y][3]);
            *(bf16x4*)(Cb + (wc * 32 + y * 16 + lrow) * 128 +
                       wr * 64 + x * 16 + lk * 4) = v;
        }

    // b) convert data f32 -> bf16, grid-stride over 1M float4s (512 blocks)
    const float4*  s = (const float4*)data;
    ushort4*       d = (ushort4*)data_b;
    const int gtid = br * 256 + t;              // 131072 threads
    #pragma unroll 4
    for (int i = gtid; i < (BATCH * NDIM * DDIM / 4); i += 131072) {
        float4 v = s[i];
        ushort4 r;
        r.x = f2bf(v.x); r.y = f2bf(v.y); r.z = f2bf(v.z); r.w = f2bf(v.w);
        d[i] = r;
    }
}

// ---------------------------------------------------------------------------
// Kernel 2 (main): 32n x 128m tile, LDS 40 KB -> 4 blocks/CU. Doubles the
// contiguous write chunk to 512 B/row (epilogue wave instr = 2 x 512 B).
// A = cw tile (128 rows m, 32 KB) @0, B = data_b tile (32 rows n, 8 KB)
// @32768, both via global_load_lds with pre-swizzled source kseg.
// Waves 2x2: wm -> 64-col m half, wn -> 16-row n half.
// Swapped mfma(A=cw rows, B=data rows) -> acc[x][j] =
//   out[n = wn*16+lrow][m = wm*64+x*16+lk*4+j].
// Epilogue: LDS transpose (32 rows x 512 B, XOR (n&7)<<4) + nt float4 stores.
// XCD-aware 1-D swizzle kept from R11 (free).
// ---------------------------------------------------------------------------
extern "C" __global__ __launch_bounds__(256, 4)
void bd_main_kernel(const unsigned short* __restrict__ data_b,
                    const unsigned short* __restrict__ cw,
                    float* __restrict__ out) {
    __shared__ __align__(16) char smem[40960];
    const int t    = threadIdx.x;
    const int lane = t & 63;
    const int w    = t >> 6;
    const int wm = w >> 1, wn = w & 1;
    const int lrow = lane & 15;
    const int lk   = lane >> 4;

    // ---- XCD-aware index derivation (bijective on [0,16384)) ----
    const int bid = blockIdx.x;
    const int c   = bid & 7;          // XCD under round-robin dispatch
    const int r0  = bid >> 3;         // 0..2047
    const int bz  = r0 >> 7;          // 16 batches
    const int q   = r0 & 127;         // 128 tiles per (XCD, bz)
    const int bx  = (c & 1) * 8 + (q & 7);      // m tile (128 cols): 0..15
    const int ny  = (c >> 1) * 16 + (q >> 3);   // n tile (32 rows): 0..63

    // ---- stage A (cw, 128 rows, 2048 chunks) @0, B (data, 32 rows) @32768 ----
    const char* Ag = (const char*)cw +     ((size_t)bz * MDIM + bx * 128) * 256;
    const char* Bg = (const char*)data_b + ((size_t)bz * NDIM + ny * 32) * 256;
    #pragma unroll
    for (int it = 0; it < 8; ++it) {
        const int cb = it * 256 + w * 64;       // wave-uniform chunk base
        const int cc = cb + lane;
        const int row = cc >> 4, ks = cc & 15;
        const int ksrc = ks ^ (row & 15);
        GLOAD_LDS16(Ag + (size_t)row * 256 + ksrc * 16, smem + cb * 16);
    }
    #pragma unroll
    for (int it = 0; it < 2; ++it) {
        const int cb = it * 256 + w * 64;
        const int cc = cb + lane;
        const int row = cc >> 4, ks = cc & 15;
        const int ksrc = ks ^ (row & 15);
        GLOAD_LDS16(Bg + (size_t)row * 256 + ksrc * 16, smem + 32768 + cb * 16);
    }
    __syncthreads();

    // ---- hoist B fragments (data rows n = wn*16 + lrow) ----
    bf16x8 b2[4];
    #pragma unroll
    for (int ks = 0; ks < 4; ++ks) {
        const int ksl = ks * 4 + lk;
        const int r = wn * 16 + lrow;
        b2[ks] = *(const bf16x8*)(smem + 32768 + r * 256 +
                                  ((ksl ^ (r & 15)) * 16));
    }

    // ---- MFMA: acc[x], n = wn*16+lrow, m = wm*64+x*16+lk*4+j ----
    f32x4 acc[4];
    #pragma unroll
    for (int x = 0; x < 4; ++x) {
        acc[x] = (f32x4){0.f, 0.f, 0.f, 0.f};
        const int r = wm * 64 + x * 16 + lrow;  // cw row (m)
        #pragma unroll
        for (int ks = 0; ks < 4; ++ks) {
            const int ksl = ks * 4 + lk;
            bf16x8 a2 = *(const bf16x8*)(smem + r * 256 + ((ksl ^ (r & 15)) * 16));
            acc[x] = __builtin_amdgcn_mfma_f32_16x16x32_bf16(
                a2, b2[ks], acc[x], 0, 0, 0);
        }
    }
    __syncthreads();    // all LDS reads done; safe to overwrite with out tile

    // ---- epilogue stage 1: acc -> LDS [32] rows x 512 B, XOR-swizzled ----
    // byte = n*512 + ((m*4) ^ ((n&7)<<4)); <=2-way on writes.
    #pragma unroll
    for (int x = 0; x < 4; ++x) {
        const int n = wn * 16 + lrow;
        const int m = wm * 64 + x * 16 + lk * 4;
        *(f32x4*)(smem + n * 512 + ((m * 4) ^ ((n & 7) << 4))) = acc[x];
    }
    __syncthreads();

    // ---- epilogue stage 2: linear re-read + coalesced nontemporal stores ----
    // 1024 float4 over 256 threads = 4 iters; wave instr = 2 rows x 512 B.
    float* ob = out + ((size_t)bz * NDIM + ny * 32) * MDIM + bx * 128;
    #pragma unroll
    for (int i = 0; i < 4; ++i) {
        const int idx = i * 256 + t;
        const int row = idx >> 5, c4 = idx & 31;
        f32x4 v = *(const f32x4*)(smem + row * 512 + ((c4 * 16) ^ ((row & 7) << 4)));
        __builtin_nontemporal_store(v, (f32x4*)(ob + (size_t)row * MDIM + c4 * 4));
    }
}

// ---------------------------------------------------------------------------
extern "C" void kernel_launch(void* const* d_in, const int* in_sizes, int n_in,
                              void* d_out, int out_size, void* d_ws, size_t ws_size,
                              hipStream_t stream) {
    const float* data = (const float*)d_in[0];  // [16,2048,128]
    const float* crit = (const float*)d_in[1];  // [16,2048,128]
    const float* W    = (const float*)d_in[2];  // [1,128,128]
    float* out = (float*)d_out;                 // [16,2048,2048]

    char* ws = (char*)d_ws;
    unsigned short* cw     = (unsigned short*)ws;              // 8 MB bf16
    unsigned short* data_b = (unsigned short*)(ws + 8388608);  // 8 MB bf16

    hipLaunchKernelGGL(bd_prep_kernel, dim3(512), dim3(256), 0, stream,
                       data, crit, W, cw, data_b);
    hipLaunchKernelGGL(bd_main_kernel, dim3(16384), dim3(256), 0, stream,
                       data_b, cw, out);
}

// Round 13
// 70.304 us; speedup vs baseline: 1.0169x; 1.0169x over previous
//
#include <hip/hip_runtime.h>
#include <hip/hip_bf16.h>
#include <stdint.h>

#define BATCH 16
#define NDIM  2048
#define MDIM  2048
#define DDIM  128   // LD == RD == 128

using bf16x8 = __attribute__((ext_vector_type(8))) short;
using bf16x4 = __attribute__((ext_vector_type(4))) short;  // 8 B
using f32x4  = __attribute__((ext_vector_type(4))) float;

// async global->LDS, 16B per lane; LDS dest is wave-uniform base + lane*16
#define GLOAD_LDS16(g, l) __builtin_amdgcn_global_load_lds( \
    (const __attribute__((address_space(1))) void*)(g),      \
    (__attribute__((address_space(3))) void*)(l), 16, 0, 0)

__device__ __forceinline__ unsigned short f2bf(float f) {
    unsigned u = __float_as_uint(f);
    u += 0x7fffu + ((u >> 16) & 1u);   // round-to-nearest-even
    return (unsigned short)(u >> 16);
}

// ---------------------------------------------------------------------------
// Stage ROWS x 128 f32 (row stride 128 floats) into LDS as bf16 with the
// XOR-16B-chunk swizzle: logical chunk (row, ks) -> byte
//   row*256 + (ks ^ (row & 15)) * 16.
// ---------------------------------------------------------------------------
template <int ITERS>
__device__ __forceinline__ void stage_f32_tile(const float* __restrict__ g,
                                               char* lds, int t) {
    #pragma unroll
    for (int it = 0; it < ITERS; ++it) {
        const int idx = it * 256 + t;           // 16B-bf16-chunk index
        const int row = idx >> 4, ks = idx & 15;
        const float4* p = (const float4*)(g + row * 128 + ks * 8);
        float4 v0 = p[0], v1 = p[1];
        bf16x8 r;
        r[0] = f2bf(v0.x); r[1] = f2bf(v0.y); r[2] = f2bf(v0.z); r[3] = f2bf(v0.w);
        r[4] = f2bf(v1.x); r[5] = f2bf(v1.y); r[6] = f2bf(v1.z); r[7] = f2bf(v1.w);
        *(bf16x8*)(lds + row * 256 + ((ks ^ (row & 15)) * 16)) = r;
    }
}

// ---------------------------------------------------------------------------
// Kernel 1 (prep): UNCHANGED from R9-R11. 512 blocks (2/CU). Per block br:
//   a) cw[br*64+m][i] = sum_j crit[br*64+m][j] * W[i][j]   (64-row tile)
//   b) grid-stride convert data f32 -> bf16.
// ---------------------------------------------------------------------------
extern "C" __global__ __launch_bounds__(256)
void bd_prep_kernel(const float* __restrict__ data,
                    const float* __restrict__ crit,
                    const float* __restrict__ W,
                    unsigned short* __restrict__ cw,
                    unsigned short* __restrict__ data_b) {
    __shared__ __align__(16) char smem[49152];
    const int t    = threadIdx.x;
    const int lane = t & 63;
    const int w    = t >> 6;
    const int wr = w >> 1, wc = w & 1;
    const int lrow = lane & 15;
    const int lk   = lane >> 4;
    const int br = blockIdx.x;  // 0..511

    stage_f32_tile<8>(W, smem, t);
    stage_f32_tile<4>(crit + (size_t)br * 64 * DDIM, smem + 32768, t);
    __syncthreads();

    // acc1[x][y]: i = wr*64 + x*16 + lk*4 + j, m = wc*32 + y*16 + lrow
    f32x4 acc1[4][2];
    #pragma unroll
    for (int x = 0; x < 4; ++x) {
        acc1[x][0] = (f32x4){0.f, 0.f, 0.f, 0.f};
        acc1[x][1] = (f32x4){0.f, 0.f, 0.f, 0.f};
    }

    #pragma unroll
    for (int ks = 0; ks < 4; ++ks) {
        const int ksl = ks * 4 + lk;
        bf16x8 a1[4], b1[2];
        #pragma unroll
        for (int x = 0; x < 4; ++x) {           // W rows (i)
            const int r = wr * 64 + x * 16 + lrow;
            a1[x] = *(const bf16x8*)(smem + r * 256 + ((ksl ^ (r & 15)) * 16));
        }
        #pragma unroll
        for (int y = 0; y < 2; ++y) {           // crit rows (m)
            const int r = wc * 32 + y * 16 + lrow;
            b1[y] = *(const bf16x8*)(smem + 32768 + r * 256 + ((ksl ^ (r & 15)) * 16));
        }
        #pragma unroll
        for (int x = 0; x < 4; ++x)
            #pragma unroll
            for (int y = 0; y < 2; ++y)
                acc1[x][y] = __builtin_amdgcn_mfma_f32_16x16x32_bf16(
                    a1[x], b1[y], acc1[x][y], 0, 0, 0);
    }

    // cw[m][i]: m = wc*32+y*16+lrow, i = wr*64+x*16+lk*4+j -> 8-B stores
    unsigned short* Cb = cw + (size_t)br * 64 * 128;
    #pragma unroll
    for (int x = 0; x < 4; ++x)
        #pragma unroll
        for (int y = 0; y < 2; ++y) {
            bf16x4 v;
            v[0] = f2bf(acc1[x][y][0]);
            v[1] = f2bf(acc1[x][y][1]);
            v[2] = f2bf(acc1[x][y][2]);
            v[3] = f2bf(acc1[x][y][3]);
            *(bf16x4*)(Cb + (wc * 32 + y * 16 + lrow) * 128 +
                       wr * 64 + x * 16 + lk * 4) = v;
        }

    // b) convert data f32 -> bf16, grid-stride over 1M float4s (512 blocks)
    const float4*  s = (const float4*)data;
    ushort4*       d = (ushort4*)data_b;
    const int gtid = br * 256 + t;              // 131072 threads
    #pragma unroll 4
    for (int i = gtid; i < (BATCH * NDIM * DDIM / 4); i += 131072) {
        float4 v = s[i];
        ushort4 r;
        r.x = f2bf(v.x); r.y = f2bf(v.y); r.z = f2bf(v.z); r.w = f2bf(v.w);
        d[i] = r;
    }
}

// ---------------------------------------------------------------------------
// Kernel 2 (main): R10/R11 body (64n x 64m tile, 32 KB LDS, 5 blocks/CU,
// XCD-aware 1-D swizzle). ONE change vs R11: epilogue stores are PLAIN
// (L2 write-back) instead of nontemporal — A/B on the store path.
// ---------------------------------------------------------------------------
extern "C" __global__ __launch_bounds__(256, 5)
void bd_main_kernel(const unsigned short* __restrict__ data_b,
                    const unsigned short* __restrict__ cw,
                    float* __restrict__ out) {
    __shared__ __align__(16) char smem[32768];
    const int t    = threadIdx.x;
    const int lane = t & 63;
    const int w    = t >> 6;
    const int wm = w >> 1, wn = w & 1;
    const int lrow = lane & 15;
    const int lk   = lane >> 4;

    // ---- XCD-aware index derivation (bijective on [0,16384)) ----
    const int bid = blockIdx.x;
    const int c   = bid & 7;          // XCD under round-robin dispatch
    const int r0  = bid >> 3;         // 0..2047
    const int bz  = r0 >> 7;          // 16 batches
    const int q   = r0 & 127;         // 128 tiles per (XCD, bz)
    const int bx  = (c & 1) * 16 + (q & 15);    // m tile 0..31
    const int ny  = (c >> 1) * 8 + (q >> 4);    // n tile 0..31

    // ---- stage A (cw, 64 rows) @0 and B (data, 64 rows) @16384 ----
    const char* Ag = (const char*)cw +     ((size_t)bz * MDIM + bx * 64) * 256;
    const char* Bg = (const char*)data_b + ((size_t)bz * NDIM + ny * 64) * 256;
    #pragma unroll
    for (int it = 0; it < 4; ++it) {
        const int cb = it * 256 + w * 64;       // wave-uniform chunk base
        const int cc = cb + lane;
        const int row = cc >> 4, ks = cc & 15;
        const int ksrc = ks ^ (row & 15);
        GLOAD_LDS16(Ag + (size_t)row * 256 + ksrc * 16, smem + cb * 16);
    }
    #pragma unroll
    for (int it = 0; it < 4; ++it) {
        const int cb = it * 256 + w * 64;
        const int cc = cb + lane;
        const int row = cc >> 4, ks = cc & 15;
        const int ksrc = ks ^ (row & 15);
        GLOAD_LDS16(Bg + (size_t)row * 256 + ksrc * 16, smem + 16384 + cb * 16);
    }
    __syncthreads();

    // ---- hoist B fragments (data rows n = wn*32 + y*16 + lrow) ----
    bf16x8 b2[2][4];
    #pragma unroll
    for (int ks = 0; ks < 4; ++ks) {
        const int ksl = ks * 4 + lk;
        #pragma unroll
        for (int y = 0; y < 2; ++y) {
            const int r = wn * 32 + y * 16 + lrow;
            b2[y][ks] = *(const bf16x8*)(smem + 16384 + r * 256 +
                                         ((ksl ^ (r & 15)) * 16));
        }
    }

    // ---- MFMA: acc[x][y], n = wn*32+y*16+lrow, m = wm*32+x*16+lk*4+j ----
    f32x4 acc[2][2];
    #pragma unroll
    for (int x = 0; x < 2; ++x) {
        acc[x][0] = (f32x4){0.f, 0.f, 0.f, 0.f};
        acc[x][1] = (f32x4){0.f, 0.f, 0.f, 0.f};
        const int r = wm * 32 + x * 16 + lrow;  // cw row (m)
        #pragma unroll
        for (int ks = 0; ks < 4; ++ks) {
            const int ksl = ks * 4 + lk;
            bf16x8 a2 = *(const bf16x8*)(smem + r * 256 + ((ksl ^ (r & 15)) * 16));
            #pragma unroll
            for (int y = 0; y < 2; ++y)
                acc[x][y] = __builtin_amdgcn_mfma_f32_16x16x32_bf16(
                    a2, b2[y][ks], acc[x][y], 0, 0, 0);
        }
    }
    __syncthreads();    // all LDS reads done; safe to overwrite with out tile

    // ---- epilogue stage 1: acc -> LDS [64] rows x 256 B, XOR-swizzled ----
    #pragma unroll
    for (int x = 0; x < 2; ++x)
        #pragma unroll
        for (int y = 0; y < 2; ++y) {
            const int n = wn * 32 + y * 16 + lrow;
            const int m = wm * 32 + x * 16 + lk * 4;
            *(f32x4*)(smem + n * 256 + ((m * 4) ^ ((n & 7) << 4))) = acc[x][y];
        }
    __syncthreads();

    // ---- epilogue stage 2: linear re-read + coalesced PLAIN stores ----
    float* ob = out + ((size_t)bz * NDIM + ny * 64) * MDIM + bx * 64;
    #pragma unroll
    for (int i = 0; i < 4; ++i) {
        const int idx = i * 256 + t;
        const int row = idx >> 4, c4 = idx & 15;
        f32x4 v = *(const f32x4*)(smem + row * 256 + ((c4 * 16) ^ ((row & 7) << 4)));
        *(f32x4*)(ob + (size_t)row * MDIM + c4 * 4) = v;
    }
}

// ---------------------------------------------------------------------------
extern "C" void kernel_launch(void* const* d_in, const int* in_sizes, int n_in,
                              void* d_out, int out_size, void* d_ws, size_t ws_size,
                              hipStream_t stream) {
    const float* data = (const float*)d_in[0];  // [16,2048,128]
    const float* crit = (const float*)d_in[1];  // [16,2048,128]
    const float* W    = (const float*)d_in[2];  // [1,128,128]
    float* out = (float*)d_out;                 // [16,2048,2048]

    char* ws = (char*)d_ws;
    unsigned short* cw     = (unsigned short*)ws;              // 8 MB bf16
    unsigned short* data_b = (unsigned short*)(ws + 8388608);  // 8 MB bf16

    hipLaunchKernelGGL(bd_prep_kernel, dim3(512), dim3(256), 0, stream,
                       data, crit, W, cw, data_b);
    hipLaunchKernelGGL(bd_main_kernel, dim3(16384), dim3(256), 0, stream,
                       data_b, cw, out);
}

// Round 14
// 64.757 us; speedup vs baseline: 1.1041x; 1.0857x over previous
//
#include <hip/hip_runtime.h>
#include <hip/hip_bf16.h>
#include <stdint.h>

#define BATCH 16
#define NDIM  2048
#define MDIM  2048
#define DDIM  128   // LD == RD == 128

using bf16x8 = __attribute__((ext_vector_type(8))) short;
using bf16x4 = __attribute__((ext_vector_type(4))) short;  // 8 B
using f32x4  = __attribute__((ext_vector_type(4))) float;

// async global->LDS, 16B per lane; LDS dest is wave-uniform base + lane*16
#define GLOAD_LDS16(g, l) __builtin_amdgcn_global_load_lds( \
    (const __attribute__((address_space(1))) void*)(g),      \
    (__attribute__((address_space(3))) void*)(l), 16, 0, 0)

__device__ __forceinline__ unsigned short f2bf(float f) {
    unsigned u = __float_as_uint(f);
    u += 0x7fffu + ((u >> 16) & 1u);   // round-to-nearest-even
    return (unsigned short)(u >> 16);
}

// ---------------------------------------------------------------------------
// Stage ROWS x 128 f32 (row stride 128 floats) into LDS as bf16 with the
// XOR-16B-chunk swizzle: logical chunk (row, ks) -> byte
//   row*256 + (ks ^ (row & 15)) * 16.
// ---------------------------------------------------------------------------
template <int ITERS>
__device__ __forceinline__ void stage_f32_tile(const float* __restrict__ g,
                                               char* lds, int t) {
    #pragma unroll
    for (int it = 0; it < ITERS; ++it) {
        const int idx = it * 256 + t;           // 16B-bf16-chunk index
        const int row = idx >> 4, ks = idx & 15;
        const float4* p = (const float4*)(g + row * 128 + ks * 8);
        float4 v0 = p[0], v1 = p[1];
        bf16x8 r;
        r[0] = f2bf(v0.x); r[1] = f2bf(v0.y); r[2] = f2bf(v0.z); r[3] = f2bf(v0.w);
        r[4] = f2bf(v1.x); r[5] = f2bf(v1.y); r[6] = f2bf(v1.z); r[7] = f2bf(v1.w);
        *(bf16x8*)(lds + row * 256 + ((ks ^ (row & 15)) * 16)) = r;
    }
}

// ---------------------------------------------------------------------------
// Kernel 1 (prep): 1024 blocks (4/CU, 40 KB LDS). Per block br:
//   a) cw[br*32+m][i] = sum_j crit[br*32+m][j] * W[i][j]   (32-row tile)
//      W staged @0 (32 KB), crit @32768 (8 KB); swapped mfma(A=W rows i,
//      B=crit rows m) -> lane holds cw[m][i0..i0+3] -> bf16x4 stores.
//      Same verified algebra, m base wc*16, single y-frag.
//   b) grid-stride convert data f32 -> bf16 (1024 blocks).
// ---------------------------------------------------------------------------
extern "C" __global__ __launch_bounds__(256, 4)
void bd_prep_kernel(const float* __restrict__ data,
                    const float* __restrict__ crit,
                    const float* __restrict__ W,
                    unsigned short* __restrict__ cw,
                    unsigned short* __restrict__ data_b) {
    __shared__ __align__(16) char smem[40960];
    const int t    = threadIdx.x;
    const int lane = t & 63;
    const int w    = t >> 6;
    const int wr = w >> 1, wc = w & 1;
    const int lrow = lane & 15;
    const int lk   = lane >> 4;
    const int br = blockIdx.x;  // 0..1023

    stage_f32_tile<8>(W, smem, t);
    stage_f32_tile<2>(crit + (size_t)br * 32 * DDIM, smem + 32768, t);
    __syncthreads();

    // acc1[x]: i = wr*64 + x*16 + lk*4 + j, m = wc*16 + lrow
    f32x4 acc1[4];
    #pragma unroll
    for (int x = 0; x < 4; ++x)
        acc1[x] = (f32x4){0.f, 0.f, 0.f, 0.f};

    #pragma unroll
    for (int ks = 0; ks < 4; ++ks) {
        const int ksl = ks * 4 + lk;
        bf16x8 a1[4], b1;
        #pragma unroll
        for (int x = 0; x < 4; ++x) {           // W rows (i)
            const int r = wr * 64 + x * 16 + lrow;
            a1[x] = *(const bf16x8*)(smem + r * 256 + ((ksl ^ (r & 15)) * 16));
        }
        {                                       // crit rows (m)
            const int r = wc * 16 + lrow;
            b1 = *(const bf16x8*)(smem + 32768 + r * 256 + ((ksl ^ (r & 15)) * 16));
        }
        #pragma unroll
        for (int x = 0; x < 4; ++x)
            acc1[x] = __builtin_amdgcn_mfma_f32_16x16x32_bf16(
                a1[x], b1, acc1[x], 0, 0, 0);
    }

    // cw[m][i]: m = wc*16+lrow, i = wr*64+x*16+lk*4+j -> 8-B stores
    unsigned short* Cb = cw + (size_t)br * 32 * 128;
    #pragma unroll
    for (int x = 0; x < 4; ++x) {
        bf16x4 v;
        v[0] = f2bf(acc1[x][0]);
        v[1] = f2bf(acc1[x][1]);
        v[2] = f2bf(acc1[x][2]);
        v[3] = f2bf(acc1[x][3]);
        *(bf16x4*)(Cb + (wc * 16 + lrow) * 128 + wr * 64 + x * 16 + lk * 4) = v;
    }

    // b) convert data f32 -> bf16, grid-stride over 1M float4s (1024 blocks)
    const float4*  s = (const float4*)data;
    ushort4*       d = (ushort4*)data_b;
    const int gtid = br * 256 + t;              // 262144 threads
    #pragma unroll 4
    for (int i = gtid; i < (BATCH * NDIM * DDIM / 4); i += 262144) {
        float4 v = s[i];
        ushort4 r;
        r.x = f2bf(v.x); r.y = f2bf(v.y); r.z = f2bf(v.z); r.w = f2bf(v.w);
        d[i] = r;
    }
}

// ---------------------------------------------------------------------------
// Kernel 2 (main): IDENTICAL to R11 best (64n x 64m tile, 32 KB LDS,
// 5 blocks/CU, XCD-aware 1-D swizzle, LDS-transpose epilogue, NT stores).
// ---------------------------------------------------------------------------
extern "C" __global__ __launch_bounds__(256, 5)
void bd_main_kernel(const unsigned short* __restrict__ data_b,
                    const unsigned short* __restrict__ cw,
                    float* __restrict__ out) {
    __shared__ __align__(16) char smem[32768];
    const int t    = threadIdx.x;
    const int lane = t & 63;
    const int w    = t >> 6;
    const int wm = w >> 1, wn = w & 1;
    const int lrow = lane & 15;
    const int lk   = lane >> 4;

    // ---- XCD-aware index derivation (bijective on [0,16384)) ----
    const int bid = blockIdx.x;
    const int c   = bid & 7;          // XCD under round-robin dispatch
    const int r0  = bid >> 3;         // 0..2047
    const int bz  = r0 >> 7;          // 16 batches
    const int q   = r0 & 127;         // 128 tiles per (XCD, bz)
    const int bx  = (c & 1) * 16 + (q & 15);    // m tile 0..31
    const int ny  = (c >> 1) * 8 + (q >> 4);    // n tile 0..31

    // ---- stage A (cw, 64 rows) @0 and B (data, 64 rows) @16384 ----
    const char* Ag = (const char*)cw +     ((size_t)bz * MDIM + bx * 64) * 256;
    const char* Bg = (const char*)data_b + ((size_t)bz * NDIM + ny * 64) * 256;
    #pragma unroll
    for (int it = 0; it < 4; ++it) {
        const int cb = it * 256 + w * 64;       // wave-uniform chunk base
        const int cc = cb + lane;
        const int row = cc >> 4, ks = cc & 15;
        const int ksrc = ks ^ (row & 15);
        GLOAD_LDS16(Ag + (size_t)row * 256 + ksrc * 16, smem + cb * 16);
    }
    #pragma unroll
    for (int it = 0; it < 4; ++it) {
        const int cb = it * 256 + w * 64;
        const int cc = cb + lane;
        const int row = cc >> 4, ks = cc & 15;
        const int ksrc = ks ^ (row & 15);
        GLOAD_LDS16(Bg + (size_t)row * 256 + ksrc * 16, smem + 16384 + cb * 16);
    }
    __syncthreads();

    // ---- hoist B fragments (data rows n = wn*32 + y*16 + lrow) ----
    bf16x8 b2[2][4];
    #pragma unroll
    for (int ks = 0; ks < 4; ++ks) {
        const int ksl = ks * 4 + lk;
        #pragma unroll
        for (int y = 0; y < 2; ++y) {
            const int r = wn * 32 + y * 16 + lrow;
            b2[y][ks] = *(const bf16x8*)(smem + 16384 + r * 256 +
                                         ((ksl ^ (r & 15)) * 16));
        }
    }

    // ---- MFMA: acc[x][y], n = wn*32+y*16+lrow, m = wm*32+x*16+lk*4+j ----
    f32x4 acc[2][2];
    #pragma unroll
    for (int x = 0; x < 2; ++x) {
        acc[x][0] = (f32x4){0.f, 0.f, 0.f, 0.f};
        acc[x][1] = (f32x4){0.f, 0.f, 0.f, 0.f};
        const int r = wm * 32 + x * 16 + lrow;  // cw row (m)
        #pragma unroll
        for (int ks = 0; ks < 4; ++ks) {
            const int ksl = ks * 4 + lk;
            bf16x8 a2 = *(const bf16x8*)(smem + r * 256 + ((ksl ^ (r & 15)) * 16));
            #pragma unroll
            for (int y = 0; y < 2; ++y)
                acc[x][y] = __builtin_amdgcn_mfma_f32_16x16x32_bf16(
                    a2, b2[y][ks], acc[x][y], 0, 0, 0);
        }
    }
    __syncthreads();    // all LDS reads done; safe to overwrite with out tile

    // ---- epilogue stage 1: acc -> LDS [64] rows x 256 B, XOR-swizzled ----
    #pragma unroll
    for (int x = 0; x < 2; ++x)
        #pragma unroll
        for (int y = 0; y < 2; ++y) {
            const int n = wn * 32 + y * 16 + lrow;
            const int m = wm * 32 + x * 16 + lk * 4;
            *(f32x4*)(smem + n * 256 + ((m * 4) ^ ((n & 7) << 4))) = acc[x][y];
        }
    __syncthreads();

    // ---- epilogue stage 2: linear re-read + coalesced nontemporal stores ----
    float* ob = out + ((size_t)bz * NDIM + ny * 64) * MDIM + bx * 64;
    #pragma unroll
    for (int i = 0; i < 4; ++i) {
        const int idx = i * 256 + t;
        const int row = idx >> 4, c4 = idx & 15;
        f32x4 v = *(const f32x4*)(smem + row * 256 + ((c4 * 16) ^ ((row & 7) << 4)));
        __builtin_nontemporal_store(v, (f32x4*)(ob + (size_t)row * MDIM + c4 * 4));
    }
}

// ---------------------------------------------------------------------------
extern "C" void kernel_launch(void* const* d_in, const int* in_sizes, int n_in,
                              void* d_out, int out_size, void* d_ws, size_t ws_size,
                              hipStream_t stream) {
    const float* data = (const float*)d_in[0];  // [16,2048,128]
    const float* crit = (const float*)d_in[1];  // [16,2048,128]
    const float* W    = (const float*)d_in[2];  // [1,128,128]
    float* out = (float*)d_out;                 // [16,2048,2048]

    char* ws = (char*)d_ws;
    unsigned short* cw     = (unsigned short*)ws;              // 8 MB bf16
    unsigned short* data_b = (unsigned short*)(ws + 8388608);  // 8 MB bf16

    hipLaunchKernelGGL(bd_prep_kernel, dim3(1024), dim3(256), 0, stream,
                       data, crit, W, cw, data_b);
    hipLaunchKernelGGL(bd_main_kernel, dim3(16384), dim3(256), 0, stream,
                       data_b, cw, out);
}